// Round 14
// baseline (118.127 us; speedup 1.0000x reference)
//
#include <hip/hip_runtime.h>

// Problem constants
#define B_   32
#define T_   2048
#define IN_  1024
#define OUT_ 256
#define M_   (B_ * T_)   // 65536

// 8-phase template GEMM: 256x256 tile, BK=64, 16 K-tiles, 8 waves (2M x 4N).
#define BM 256
#define BN 256
#define BK 64
#define NKT (IN_ / BK)      // 16 K-tiles
#define THREADS 512
#define TPB (T_ / BM)       // 8 time-tiles per batch

// Scan chunking: LC=32 -> 8 chunks per block tile.
#define LC 32
#define NCHUNK (BM / LC)    // 8
#define XPAD 264            // x-tile row pitch (bf16)

// LDS: staging = 2 x 32KB (A bf16 [256][64]) + 2 x 32KB (B bf16 [256][64]) = 128KB
//      overlay: x-tile [256][264] bf16 = 132KB + ce 8KB + ca 8KB = 148KB
#define ABUF_OFF(c) ((c) * 32768)
#define BBUF_OFF(c) (65536 + (c) * 32768)
#define XT_BYTES (BM * XPAD * 2)                 // 135168
#define SMEM_BYTES (XT_BYTES + 2 * NCHUNK * OUT_ * 4)   // 151552

typedef __attribute__((ext_vector_type(4))) float f32x4;
typedef __attribute__((ext_vector_type(8))) __bf16 bf16x8;

// fp32 -> bf16 round-to-nearest-even
__device__ __forceinline__ unsigned int f2bf_pk(float a, float b) {
    unsigned int ua = __float_as_uint(a);
    unsigned int ub = __float_as_uint(b);
    ua = (ua + 0x7fffu + ((ua >> 16) & 1u)) >> 16;
    ub = (ub + 0x7fffu + ((ub >> 16) & 1u)) >> 16;
    return ua | (ub << 16);
}
__device__ __forceinline__ unsigned short f2bf1(float a) {
    unsigned int ua = __float_as_uint(a);
    return (unsigned short)((ua + 0x7fffu + ((ua >> 16) & 1u)) >> 16);
}
__device__ __forceinline__ float bf2f(unsigned short s) {
    return __uint_as_float((unsigned int)s << 16);
}

// async global -> LDS, 16B per lane; lds dest = wave-uniform base + lane*16
__device__ __forceinline__ void gload_lds16(const void* g, void* l) {
    __builtin_amdgcn_global_load_lds(
        (const __attribute__((address_space(1))) void*)g,
        (__attribute__((address_space(3))) void*)l, 16, 0, 0);
}

// ---------------------------------------------------------------------------
// One-shot W fp32 -> bf16 (512 KB) + zero ticket/flag region (block 0).
// ---------------------------------------------------------------------------
__global__ __launch_bounds__(256) void convert_w_init(const float* __restrict__ W,
                                                      unsigned short* __restrict__ Wb,
                                                      unsigned int* __restrict__ flags) {
    const int i = blockIdx.x * 256 + threadIdx.x;  // float4 index
    const float4 v = ((const float4*)W)[i];
    uint2 o;
    o.x = f2bf_pk(v.x, v.y);
    o.y = f2bf_pk(v.z, v.w);
    ((uint2*)Wb)[i] = o;
    if (blockIdx.x == 0) {
        flags[threadIdx.x] = 0u;
        flags[256 + threadIdx.x] = 0u;
        if (threadIdx.x == 0) flags[512] = 0u;   // ticket
    }
}

// ---------------------------------------------------------------------------
// Fused 8-phase kernel. Per K-tile (4 phases):
//   P0: ds_read B frags(8)+A frags mi{0,1}(4) | barrier | lgkm0 | prio1 16MFMA prio0 | barrier
//   P1: ds_read A mi{2,3} + 2 B-gloads(kt+2)  | ... (B-gloads only after P0 close
//   P2: ds_read A mi{4,5} + 1 B-gload         |      barrier: current B buffer's
//   P3: ds_read A mi{6,7} + 1 B-gload | barrier | lgkm0 | MFMA | vmcnt(4) | barrier
//   tile end: cvt+ds_write A(kt+2) (regs loaded last tile) + issue A(kt+3) loads.
// FIFO: per tile issues [B(kt+2)x4, A(kt+3)x8]; at P3, outstanding =
// B(kt+1)x4 + A(kt+2)x8 + B(kt+2)x4 = 16 -> vmcnt(4) retires B(kt+1)+A(kt+2),
// keeps B(kt+2) in flight across the barrier. Never drained mid-loop.
// LDS swizzle: granule phys = g ^ (row&7) on A-writes/reads and B (via
// pre-swizzled gload source involution) -> frag ds_read_b128 ~2-way (free).
// Accumulator K-order identical to the verified BK=32 kernel -> bit-identical.
// ---------------------------------------------------------------------------
__global__ __launch_bounds__(THREADS, 2) void fused_all(
    const float* __restrict__ A, const unsigned short* __restrict__ Wb,
    const float* __restrict__ bias, const float* __restrict__ decay,
    float* __restrict__ out, float* __restrict__ localend,
    unsigned int* __restrict__ flags) {
    __shared__ __align__(16) char smem[SMEM_BYTES];
    __shared__ int s_tk;

    const int tid  = threadIdx.x;
    const int lane = tid & 63;
    const int wid  = tid >> 6;
    const int wm   = wid >> 2;     // 0..1  (M direction, 128 rows each)
    const int wn   = wid & 3;      // 0..3  (N direction, 64 cols each)
    const int l15  = lane & 15;
    const int l4   = lane >> 4;    // 0..3

    if (tid == 0) s_tk = (int)atomicAdd(&flags[512], 1u);   // device-scope ticket
    __syncthreads();
    const int p    = s_tk;           // m-tile position, 0..255
    const int jb   = p & (TPB - 1);  // tile index within batch
    const int base = p - jb;
    const int bm0  = p * BM;

    // --- A staging: thread -> (row, half). 8 float4 regs per tile. ---
    const int rA = tid >> 1;         // 0..255
    const int hA = tid & 1;          // k-half (32 floats)
    const float* gsrcA = A + (size_t)(bm0 + rA) * IN_ + hA * 32;

    // --- B gload source (involution pre-swizzle): instr i covers granules
    //     G = (wid*4+i)*64 + lane; r=G>>3, pg=G&7, g=pg^(r&7). ---
    const unsigned short* gsrcBl[4];
    int ldsBbase[4];
#pragma unroll
    for (int i = 0; i < 4; ++i) {
        const int G = (wid * 4 + i) * 64 + lane;
        const int r = G >> 3;
        const int g = (G & 7) ^ (r & 7);
        gsrcBl[i] = Wb + (size_t)r * IN_ + g * 8;
        ldsBbase[i] = (wid * 4 + i) * 1024;
    }

    f32x4 acc[8][4] = {};
    float4 av[8];

    auto loadAv = [&](int kt) {
#pragma unroll
        for (int j = 0; j < 8; ++j)
            av[j] = *(const float4*)(gsrcA + kt * BK + j * 4);
    };
    auto writeAv = [&](int buf) {
#pragma unroll
        for (int j2 = 0; j2 < 4; ++j2) {
            uint4 pk;
            pk.x = f2bf_pk(av[2 * j2].x,     av[2 * j2].y);
            pk.y = f2bf_pk(av[2 * j2].z,     av[2 * j2].w);
            pk.z = f2bf_pk(av[2 * j2 + 1].x, av[2 * j2 + 1].y);
            pk.w = f2bf_pk(av[2 * j2 + 1].z, av[2 * j2 + 1].w);
            const int g = hA * 4 + j2;
            *(uint4*)&smem[ABUF_OFF(buf) + rA * 128 + ((g ^ (rA & 7)) << 4)] = pk;
        }
    };

    // --- prologue: B(0)->buf0, B(1)->buf1; A(0),A(1) cvt->LDS; A(2) in flight ---
#pragma unroll
    for (int i = 0; i < 4; ++i) gload_lds16(gsrcBl[i],      smem + BBUF_OFF(0) + ldsBbase[i]);
#pragma unroll
    for (int i = 0; i < 4; ++i) gload_lds16(gsrcBl[i] + BK, smem + BBUF_OFF(1) + ldsBbase[i]);
    loadAv(0);
    asm volatile("s_waitcnt vmcnt(0)" ::: "memory");
    __builtin_amdgcn_sched_barrier(0);
    writeAv(0);
    loadAv(1);
    asm volatile("s_waitcnt vmcnt(0)" ::: "memory");
    __builtin_amdgcn_sched_barrier(0);
    writeAv(1);
    loadAv(2);                                  // stays in flight (8 entries)
    asm volatile("s_waitcnt lgkmcnt(0)" ::: "memory");
    __builtin_amdgcn_s_barrier();
    __builtin_amdgcn_sched_barrier(0);

#define LOAD_AF(q)                                                              \
    {                                                                           \
        _Pragma("unroll")                                                       \
        for (int j = 0; j < 2; ++j) {                                           \
            _Pragma("unroll")                                                   \
            for (int ks = 0; ks < 2; ++ks) {                                    \
                const int row = wm * 128 + (2 * (q) + j) * 16 + l15;            \
                const int g   = ks * 4 + l4;                                    \
                af[j][ks] = *(const bf16x8*)&smem[ABUF_OFF(cur) + row * 128 +   \
                                                  ((g ^ (row & 7)) << 4)];      \
            }                                                                   \
        }                                                                       \
    }
#define MFMA_Q(q)                                                               \
    {                                                                           \
        _Pragma("unroll")                                                       \
        for (int j = 0; j < 2; ++j) {                                           \
            _Pragma("unroll")                                                   \
            for (int ni = 0; ni < 4; ++ni) {                                    \
                _Pragma("unroll")                                               \
                for (int ks = 0; ks < 2; ++ks)                                  \
                    acc[2 * (q) + j][ni] = __builtin_amdgcn_mfma_f32_16x16x32_bf16( \
                        af[j][ks], bfr[ni][ks], acc[2 * (q) + j][ni], 0, 0, 0); \
            }                                                                   \
        }                                                                       \
    }
#define PHASE_MID()                                                             \
    __builtin_amdgcn_s_barrier();                                               \
    asm volatile("s_waitcnt lgkmcnt(0)" ::: "memory");                          \
    __builtin_amdgcn_sched_barrier(0);                                          \
    __builtin_amdgcn_s_setprio(1);
#define PHASE_END()                                                             \
    __builtin_amdgcn_s_setprio(0);                                              \
    __builtin_amdgcn_s_barrier();

    for (int kt = 0; kt < NKT; ++kt) {
        const int cur = kt & 1;
        const int kt2 = kt + 2;
        const bool doB = (kt2 < NKT);
        bf16x8 bfr[4][2];
        bf16x8 af[2][2];
        // ---- P0: B frags (8) + A mi{0,1} (4) ----
#pragma unroll
        for (int ni = 0; ni < 4; ++ni)
#pragma unroll
            for (int ks = 0; ks < 2; ++ks) {
                const int col = wn * 64 + ni * 16 + l15;
                const int g   = ks * 4 + l4;
                bfr[ni][ks] = *(const bf16x8*)&smem[BBUF_OFF(cur) + col * 128 +
                                                    ((g ^ (col & 7)) << 4)];
            }
        LOAD_AF(0)
        PHASE_MID()
        MFMA_Q(0)
        PHASE_END()
        // ---- P1: A mi{2,3} + 2 B-gloads ----
        LOAD_AF(1)
        if (doB) {
            gload_lds16(gsrcBl[0] + kt2 * BK, smem + BBUF_OFF(cur) + ldsBbase[0]);
            gload_lds16(gsrcBl[1] + kt2 * BK, smem + BBUF_OFF(cur) + ldsBbase[1]);
        }
        PHASE_MID()
        MFMA_Q(1)
        PHASE_END()
        // ---- P2: A mi{4,5} + 1 B-gload ----
        LOAD_AF(2)
        if (doB) gload_lds16(gsrcBl[2] + kt2 * BK, smem + BBUF_OFF(cur) + ldsBbase[2]);
        PHASE_MID()
        MFMA_Q(2)
        PHASE_END()
        // ---- P3: A mi{6,7} + 1 B-gload; counted vmcnt; barrier ----
        LOAD_AF(3)
        if (doB) gload_lds16(gsrcBl[3] + kt2 * BK, smem + BBUF_OFF(cur) + ldsBbase[3]);
        __builtin_amdgcn_s_barrier();
        asm volatile("s_waitcnt lgkmcnt(0)" ::: "memory");
        __builtin_amdgcn_sched_barrier(0);
        __builtin_amdgcn_s_setprio(1);
        MFMA_Q(3)
        __builtin_amdgcn_s_setprio(0);
        if (kt <= NKT - 3) {
            asm volatile("s_waitcnt vmcnt(4)" ::: "memory");   // retire B(kt+1)+A(kt+2)
        } else {
            asm volatile("s_waitcnt vmcnt(0)" ::: "memory");   // tail
        }
        __builtin_amdgcn_sched_barrier(0);
        __builtin_amdgcn_s_barrier();
        __builtin_amdgcn_sched_barrier(0);
        // ---- tile end: write A(kt+2) (regs from last tile); issue A(kt+3) ----
        if (kt2 < NKT) writeAv(cur);
        if (kt + 3 < NKT) loadAv(kt + 3);
    }
    __syncthreads();   // staging dead; smem becomes x-tile + ce + ca

    unsigned short* xt = (unsigned short*)smem;
    float* ceL = (float*)(smem + XT_BYTES);          // [8][256]
    float* caL = ceL + NCHUNK * OUT_;                // [8][256]

    // --- x = acc + bias -> bf16 x-tile [256][XPAD] ---
#pragma unroll
    for (int ni = 0; ni < 4; ++ni) {
        const int col = wn * 64 + ni * 16 + l15;
        const float bv = bias[col];
#pragma unroll
        for (int mi = 0; mi < 8; ++mi) {
            const int r0 = wm * 128 + mi * 16 + (l4 << 2);
#pragma unroll
            for (int r = 0; r < 4; ++r)
                xt[(r0 + r) * XPAD + col] = f2bf1(acc[mi][ni][r] + bv);
        }
    }
    __syncthreads();

    // --- chunk-local scans (seed 0) -> ceL ---
    for (int task = tid; task < NCHUNK * OUT_; task += THREADS) {
        const int cl  = task >> 8;
        const int col = task & 255;
        const float alpha = decay[col];
        const float om = 1.0f - alpha;
        float u = 0.0f;
        const unsigned short* px = &xt[(cl * LC) * XPAD + col];
#pragma unroll
        for (int t = 0; t < LC; ++t)
            u = fmaf(alpha, u, om * bf2f(px[t * XPAD]));
        ceL[cl * OUT_ + col] = u;
    }
    __syncthreads();

    // --- fold 8 chunks -> 256-step composite; publish (AGENT scope) ---
    float a32 = 0.f, a256 = 0.f;
    if (tid < OUT_) {
        const float alpha_c = decay[tid];
        a32 = alpha_c;
#pragma unroll
        for (int i = 1; i < LC; ++i) a32 *= alpha_c;   // alpha^32
        float t2 = a32 * a32;                          // ^64
        t2 = t2 * t2;                                  // ^128
        a256 = t2 * t2;                                // ^256
        float le = ceL[tid];
#pragma unroll
        for (int c = 1; c < NCHUNK; ++c) le = fmaf(a32, le, ceL[c * OUT_ + tid]);
        __hip_atomic_store(&localend[(size_t)p * OUT_ + tid], le,
                           __ATOMIC_RELAXED, __HIP_MEMORY_SCOPE_AGENT);
    }
    __syncthreads();   // payload stores drained before flag
    if (tid == 0)
        __hip_atomic_store(&flags[p], 1u, __ATOMIC_RELEASE, __HIP_MEMORY_SCOPE_AGENT);
    if (tid < jb) {
        while (__hip_atomic_load(&flags[base + tid], __ATOMIC_ACQUIRE,
                                 __HIP_MEMORY_SCOPE_AGENT) == 0u)
            __builtin_amdgcn_s_sleep(2);
    }
    __syncthreads();

    // --- compose carry-in: fold predecessors' composites with alpha^256 ---
    if (tid < OUT_) {
        float cin = 0.0f;
#pragma unroll
        for (int i = 0; i < TPB - 1; ++i) {
            float v = __hip_atomic_load(&localend[(size_t)(base + i) * OUT_ + tid],
                                        __ATOMIC_RELAXED, __HIP_MEMORY_SCOPE_AGENT);
            if (i < jb) cin = fmaf(a256, cin, v);
        }
        caL[tid] = cin;
        float c = cin;
#pragma unroll
        for (int k = 1; k < NCHUNK; ++k) {
            c = fmaf(a32, c, ceL[(k - 1) * OUT_ + tid]);
            caL[k * OUT_ + tid] = c;
        }
    }
    __syncthreads();

    // --- final scan: seed from chunk carry, write u straight to out ---
    for (int task = tid; task < NCHUNK * OUT_; task += THREADS) {
        const int cl  = task >> 8;
        const int col = task & 255;
        const float alpha = decay[col];
        const float om = 1.0f - alpha;
        float u = caL[cl * OUT_ + col];
        const unsigned short* px = &xt[(cl * LC) * XPAD + col];
        float* po = &out[(size_t)(bm0 + cl * LC) * OUT_ + col];
#pragma unroll
        for (int t = 0; t < LC; ++t) {
            u = fmaf(alpha, u, om * bf2f(px[t * XPAD]));
            po[(size_t)t * OUT_] = u;
        }
    }
}

// ---------------------------------------------------------------------------
// Fallback path (ws too small): fp32 GEMM + simple scan, known good.
// ---------------------------------------------------------------------------
__global__ __launch_bounds__(256) void gemm_bias(const float* __restrict__ A,
                                                 const float* __restrict__ W,
                                                 const float* __restrict__ bias,
                                                 float* __restrict__ C) {
    __shared__ float As[16][64 + 4];
    __shared__ float Ws[16][64 + 4];
    const int bm = blockIdx.y * 64;
    const int bn = blockIdx.x * 64;
    const int tid = threadIdx.x;
    const int tx = tid & 15, ty = tid >> 4;
    const int lr = tid >> 2, lc = (tid & 3) << 2;
    float acc[4][4] = {};
    const float* Ap = A + (size_t)(bm + lr) * IN_ + lc;
    const float* Wp = W + (size_t)(bn + lr) * IN_ + lc;
    for (int k0 = 0; k0 < IN_; k0 += 16) {
        const float4 a = *(const float4*)(Ap + k0);
        const float4 w = *(const float4*)(Wp + k0);
        __syncthreads();
        As[lc + 0][lr] = a.x; As[lc + 1][lr] = a.y; As[lc + 2][lr] = a.z; As[lc + 3][lr] = a.w;
        Ws[lc + 0][lr] = w.x; Ws[lc + 1][lr] = w.y; Ws[lc + 2][lr] = w.z; Ws[lc + 3][lr] = w.w;
        __syncthreads();
#pragma unroll
        for (int kk = 0; kk < 16; ++kk) {
            const float4 av = *(const float4*)&As[kk][ty << 2];
            const float4 wv = *(const float4*)&Ws[kk][tx << 2];
            const float a0[4] = {av.x, av.y, av.z, av.w};
            const float w0[4] = {wv.x, wv.y, wv.z, wv.w};
#pragma unroll
            for (int i = 0; i < 4; ++i)
#pragma unroll
                for (int j = 0; j < 4; ++j) acc[i][j] = fmaf(a0[i], w0[j], acc[i][j]);
        }
    }
#pragma unroll
    for (int i = 0; i < 4; ++i) {
        const size_t row = (size_t)(bm + (ty << 2) + i);
#pragma unroll
        for (int j = 0; j < 4; ++j)
            C[row * OUT_ + bn + (tx << 2) + j] = acc[i][j] + bias[bn + (tx << 2) + j];
    }
}

__global__ __launch_bounds__(OUT_) void scan_simple(float* __restrict__ C,
                                                    const float* __restrict__ decay) {
    const int b = blockIdx.x;
    const int o = threadIdx.x;
    const float alpha = decay[o];
    const float om = 1.0f - alpha;
    float u = 0.0f;
    float* p = C + (size_t)b * T_ * OUT_ + o;
    for (int t = 0; t < T_; ++t) {
        const float x = p[(size_t)t * OUT_];
        u = fmaf(alpha, u, om * x);
        p[(size_t)t * OUT_] = u;
    }
}

extern "C" void kernel_launch(void* const* d_in, const int* in_sizes, int n_in,
                              void* d_out, int out_size, void* d_ws, size_t ws_size,
                              hipStream_t stream) {
    const float* inputs = (const float*)d_in[0];
    const float* weight = (const float*)d_in[1];
    const float* bias   = (const float*)d_in[2];
    const float* decay  = (const float*)d_in[3];
    float* out = (float*)d_out;

    // Workspace layout
    const size_t wb_bytes = (size_t)OUT_ * IN_ * 2;                 // 512 KB bf16 W
    const size_t le_bytes = (size_t)(M_ / BM) * OUT_ * 4;           // 256 KB localend
    const size_t fl_bytes = 4096;                                   // flags+ticket
    const size_t need = wb_bytes + le_bytes + fl_bytes;

    if (ws_size >= need) {
        char* w = (char*)d_ws;
        unsigned short* Wb  = (unsigned short*)w;
        float* localend     = (float*)(w + wb_bytes);
        unsigned int* flags = (unsigned int*)(w + wb_bytes + le_bytes);

        convert_w_init<<<(OUT_ * IN_ / 4) / 256, 256, 0, stream>>>(weight, Wb, flags);
        fused_all<<<M_ / BM, THREADS, 0, stream>>>(inputs, Wb, bias, decay,
                                                   out, localend, flags);
    } else {
        dim3 g(OUT_ / 64, M_ / 64);
        gemm_bias<<<g, 256, 0, stream>>>(inputs, weight, bias, out);
        scan_simple<<<B_, OUT_, 0, stream>>>(out, decay);
    }
}